// Round 1
// 824.500 us; speedup vs baseline: 1.0076x; 1.0076x over previous
//
#include <hip/hip_runtime.h>
#include <math.h>

#define EMBED 128
#define NPOS  10
#define NNEG  50
#define NTOT  (NPOS + NNEG)   // 60
#define NPASS (NTOT / 4)      // 15 passes, 4 samples (16-lane groups) per pass
#define DEPTH 3               // software-pipeline depth (passes in flight = 12 rows)

// Fast stable log-sigmoid: log(1/(1+e^-x)) = min(x,0) - log(1 + e^-|x|).
// __logf(1+t) with t in (0,1] replaces the ~20-instr log1pf libm sequence;
// abs error ~1e-6 per term, 60 terms -> ~6e-5 worst case, within tolerance.
__device__ __forceinline__ float logsig_fast(float x) {
    return fminf(x, 0.0f) - __logf(1.0f + __expf(-fabsf(x)));
}

// One wave (64 lanes) per batch element.
// Lane layout: g = lane>>4 selects one of 4 concurrent samples,
//              e = lane&15 selects an 8-float slice of the 128-dim row.
// Explicit DEPTH-pass pipeline: the label shuffle (ds_bpermute, ~100cy) and
// the row load (HBM, ~900cy) for pass p+DEPTH are issued before pass p's
// compute consumes its data, so neither sits on the critical path.
// __launch_bounds__(256,8): force VGPR<=64 -> 8 waves/SIMD for max gather MLP.
__global__ __launch_bounds__(256, 8) void nsloss_kernel(
    const int*   __restrict__ input_labels,   // (B,1)
    const int*   __restrict__ pos_labels,     // (B,NPOS)
    const int*   __restrict__ neg_labels,     // (B,NNEG)
    const float* __restrict__ in_embed,       // (V,EMBED)
    const float* __restrict__ out_embed,      // (V,EMBED)
    float*       __restrict__ out,            // (B,)
    int batch)
{
    const int wid  = (int)((blockIdx.x * blockDim.x + threadIdx.x) >> 6);
    const int lane = (int)(threadIdx.x & 63);
    if (wid >= batch) return;
    const int b = wid;
    const int g = lane >> 4;     // sample group 0..3
    const int e = lane & 15;     // slice index: floats [8e, 8e+8)

    // Input embedding slice (identical across the 4 groups; broadcast from L1)
    const long vrow = (long)input_labels[b] * EMBED;
    const float4 v0 = *reinterpret_cast<const float4*>(in_embed + vrow + 8 * e);
    const float4 v1 = *reinterpret_cast<const float4*>(in_embed + vrow + 8 * e + 4);

    // Preload all 60 labels for this batch element: lane s holds label of sample s.
    int myLabel = 0;
    if (lane < NPOS)      myLabel = pos_labels[(long)b * NPOS + lane];
    else if (lane < NTOT) myLabel = neg_labels[(long)b * NNEG + (lane - NPOS)];

    // Prologue: fill the pipeline with the first DEPTH passes' rows.
    float4 q0[DEPTH], q1[DEPTH];
    #pragma unroll
    for (int i = 0; i < DEPTH; ++i) {
        const int lb = __shfl(myLabel, 4 * i + g, 64);
        const float* __restrict__ r = out_embed + (long)lb * EMBED + 8 * e;
        q0[i] = *reinterpret_cast<const float4*>(r);
        q1[i] = *reinterpret_cast<const float4*>(r + 4);
    }

    float loss = 0.0f;

    #pragma unroll
    for (int p = 0; p < NPASS; ++p) {
        // Issue pass p+DEPTH's shuffle+load before consuming pass p (no dep).
        float4 n0, n1;
        const bool pf = (p + DEPTH < NPASS);
        if (pf) {
            const int lb = __shfl(myLabel, 4 * (p + DEPTH) + g, 64);
            const float* __restrict__ r = out_embed + (long)lb * EMBED + 8 * e;
            n0 = *reinterpret_cast<const float4*>(r);
            n1 = *reinterpret_cast<const float4*>(r + 4);
        }

        // Consume pass p (waits only on the load issued DEPTH passes ago).
        // p % DEPTH is compile-time constant after full unroll -> stays in regs.
        const float4 r0 = q0[p % DEPTH];
        const float4 r1 = q1[p % DEPTH];

        float d = v0.x * r0.x + v0.y * r0.y + v0.z * r0.z + v0.w * r0.w
                + v1.x * r1.x + v1.y * r1.y + v1.z * r1.z + v1.w * r1.w;

        // 16-lane butterfly (xor<16 stays within the group)
        d += __shfl_xor(d, 1, 64);
        d += __shfl_xor(d, 2, 64);
        d += __shfl_xor(d, 4, 64);
        d += __shfl_xor(d, 8, 64);

        // positives use +dot, negatives use -dot (ref: logsig(-neg_dot));
        // 4*p+g < NPOS folds to a constant for all p except p==2 after unroll.
        loss += logsig_fast((4 * p + g < NPOS) ? d : -d);

        if (pf) {
            q0[p % DEPTH] = n0;
            q1[p % DEPTH] = n1;
        }
    }

    // Sum the 4 group losses (each lane in a group holds identical value)
    loss += __shfl_xor(loss, 16, 64);
    loss += __shfl_xor(loss, 32, 64);

    if (lane == 0) out[b] = -loss;
}

extern "C" void kernel_launch(void* const* d_in, const int* in_sizes, int n_in,
                              void* d_out, int out_size, void* d_ws, size_t ws_size,
                              hipStream_t stream) {
    const int*   input_labels = (const int*)d_in[0];
    const int*   pos_labels   = (const int*)d_in[1];
    const int*   neg_labels   = (const int*)d_in[2];
    const float* in_embed     = (const float*)d_in[3];
    const float* out_embed    = (const float*)d_in[4];
    float*       out          = (float*)d_out;

    const int batch = in_sizes[0];
    const int wavesPerBlock = 4;              // 256 threads
    const int blocks = (batch + wavesPerBlock - 1) / wavesPerBlock;

    nsloss_kernel<<<blocks, wavesPerBlock * 64, 0, stream>>>(
        input_labels, pos_labels, neg_labels, in_embed, out_embed, out, batch);
}

// Round 2
// 824.242 us; speedup vs baseline: 1.0079x; 1.0003x over previous
//
#include <hip/hip_runtime.h>
#include <math.h>

#define EMBED  128
#define NPOS   10
#define NNEG   50
#define NTOT   (NPOS + NNEG)   // 60
#define NPASS  (NTOT / 2)      // 30 passes, 2 samples (32-lane groups) per pass
#define DEPTH  8               // row-load pipeline depth (16 rows in flight/wave)

// Fast stable log-sigmoid: log(1/(1+e^-x)) = min(x,0) - log(1 + e^-|x|).
__device__ __forceinline__ float logsig_fast(float x) {
    return fminf(x, 0.0f) - __logf(1.0f + __expf(-fabsf(x)));
}

// One wave (64 lanes) per batch element.
// Lane layout: g = lane>>5 selects one of 2 concurrent samples,
//              e = lane&31 selects a contiguous float4 slice of the 128-dim row.
// Each row-load instruction is a fully-contiguous 512B gather per 32-lane group:
// every 128B cache line is requested exactly once, fully covered (vs the old
// 16-lane/row mapping where each line was touched by TWO partial 64B requests).
// DEPTH=8 pipeline: 8 dwordx4 loads (16 rows) in flight per wave; queue slot is
// one float4 (4 VGPR) so the whole kernel fits 64 VGPR -> 8 waves/SIMD.
__global__ __launch_bounds__(256, 8) void nsloss_kernel(
    const int*   __restrict__ input_labels,   // (B,1)
    const int*   __restrict__ pos_labels,     // (B,NPOS)
    const int*   __restrict__ neg_labels,     // (B,NNEG)
    const float* __restrict__ in_embed,       // (V,EMBED)
    const float* __restrict__ out_embed,      // (V,EMBED)
    float*       __restrict__ out,            // (B,)
    int batch)
{
    const int wid  = (int)((blockIdx.x * blockDim.x + threadIdx.x) >> 6);
    const int lane = (int)(threadIdx.x & 63);
    if (wid >= batch) return;
    const int b = wid;
    const int g = lane >> 5;     // sample group 0..1
    const int e = lane & 31;     // slice index: floats [4e, 4e+4)

    // Input embedding slice (identical across the 2 groups; broadcast from L1)
    const long vrow = (long)input_labels[b] * EMBED;
    const float4 v = *reinterpret_cast<const float4*>(in_embed + vrow + 4 * e);

    // Preload all 60 labels for this batch element: lane s holds label of sample s.
    int myLabel = 0;
    if (lane < NPOS)      myLabel = pos_labels[(long)b * NPOS + lane];
    else if (lane < NTOT) myLabel = neg_labels[(long)b * NNEG + (lane - NPOS)];

    // Prologue: fill the pipeline with the first DEPTH passes' rows.
    float4 q[DEPTH];
    #pragma unroll
    for (int i = 0; i < DEPTH; ++i) {
        const int lb = __shfl(myLabel, 2 * i + g, 64);
        q[i] = *reinterpret_cast<const float4*>(out_embed + (long)lb * EMBED + 4 * e);
    }

    float loss = 0.0f;

    #pragma unroll
    for (int p = 0; p < NPASS; ++p) {
        // Issue pass p+DEPTH's shuffle+load before consuming pass p (no dep).
        float4 n;
        const bool pf = (p + DEPTH < NPASS);
        if (pf) {
            const int lb = __shfl(myLabel, 2 * (p + DEPTH) + g, 64);
            n = *reinterpret_cast<const float4*>(out_embed + (long)lb * EMBED + 4 * e);
        }

        // Consume pass p (waits only on the load issued DEPTH passes ago).
        // p % DEPTH is compile-time constant after full unroll -> stays in regs.
        const float4 r = q[p % DEPTH];

        float d = v.x * r.x + v.y * r.y + v.z * r.z + v.w * r.w;

        // 32-lane butterfly (xor<32 stays within the group)
        d += __shfl_xor(d, 1, 64);
        d += __shfl_xor(d, 2, 64);
        d += __shfl_xor(d, 4, 64);
        d += __shfl_xor(d, 8, 64);
        d += __shfl_xor(d, 16, 64);

        // Sample index is s = 2p+g; s < NPOS=10 <=> p < 5 for both g -> folds
        // to a compile-time constant sign per unrolled iteration.
        loss += logsig_fast((p < NPOS / 2) ? d : -d);

        if (pf) q[p % DEPTH] = n;
    }

    // Sum the 2 group losses (each lane in a group holds identical value)
    loss += __shfl_xor(loss, 32, 64);

    if (lane == 0) out[b] = -loss;
}

extern "C" void kernel_launch(void* const* d_in, const int* in_sizes, int n_in,
                              void* d_out, int out_size, void* d_ws, size_t ws_size,
                              hipStream_t stream) {
    const int*   input_labels = (const int*)d_in[0];
    const int*   pos_labels   = (const int*)d_in[1];
    const int*   neg_labels   = (const int*)d_in[2];
    const float* in_embed     = (const float*)d_in[3];
    const float* out_embed    = (const float*)d_in[4];
    float*       out          = (float*)d_out;

    const int batch = in_sizes[0];
    const int wavesPerBlock = 4;              // 256 threads
    const int blocks = (batch + wavesPerBlock - 1) / wavesPerBlock;

    nsloss_kernel<<<blocks, wavesPerBlock * 64, 0, stream>>>(
        input_labels, pos_labels, neg_labels, in_embed, out_embed, out, batch);
}